// Round 9
// baseline (10909.349 us; speedup 1.0000x reference)
//
#include <hip/hip_runtime.h>

#define BB 16
#define SS 256
#define NVOCAB 32000
#define NEMB 300

// ---- recurrence geometry ----
#define CHUNK 6            // h-indices per block (multiple of 3: chunk-aligned publish)
#define NT 384             // threads per rec block (48 k-slices x 8 row-groups)
#define NSTR 384           // hx cols (allocation)

typedef float f4_t __attribute__((ext_vector_type(4)));
typedef unsigned int u4_t __attribute__((ext_vector_type(4)));
typedef short bf16x8 __attribute__((ext_vector_type(8)));
typedef float f32x4 __attribute__((ext_vector_type(4)));
typedef unsigned short ushort_t;

// unaligned-safe float4 global load (rows of W are only 4B-aligned when H=1150)
__device__ __forceinline__ f4_t load_f4u(const float* p) {
    f4_t v;
    __builtin_memcpy(&v, p, sizeof(f4_t));
    return v;
}

// LLC-coherent publish: 16B store (value+tag atomic at LLC) + drain inside asm
__device__ __forceinline__ void llc_store_u4_drain(u4_t* p, u4_t v) {
    asm volatile("global_store_dwordx4 %0, %1, off sc0 sc1\n\t"
                 "s_waitcnt vmcnt(0)" :: "v"(p), "v"(v) : "memory");
}

// 16 coherent dwordx4 loads (one base + immediate offsets 0..3840) issued and
// WAITED inside one asm block. No in-flight dest reg crosses compiler code.
__device__ __forceinline__ void llc_load16_wait(
        u4_t& a0, u4_t& a1, u4_t& a2, u4_t& a3,
        u4_t& a4, u4_t& a5, u4_t& a6, u4_t& a7,
        u4_t& a8, u4_t& a9, u4_t& a10, u4_t& a11,
        u4_t& a12, u4_t& a13, u4_t& a14, u4_t& a15,
        const u4_t* p) {
    asm volatile(
        "global_load_dwordx4 %0, %16, off sc0 sc1\n\t"
        "global_load_dwordx4 %1, %16, off offset:256 sc0 sc1\n\t"
        "global_load_dwordx4 %2, %16, off offset:512 sc0 sc1\n\t"
        "global_load_dwordx4 %3, %16, off offset:768 sc0 sc1\n\t"
        "global_load_dwordx4 %4, %16, off offset:1024 sc0 sc1\n\t"
        "global_load_dwordx4 %5, %16, off offset:1280 sc0 sc1\n\t"
        "global_load_dwordx4 %6, %16, off offset:1536 sc0 sc1\n\t"
        "global_load_dwordx4 %7, %16, off offset:1792 sc0 sc1\n\t"
        "global_load_dwordx4 %8, %16, off offset:2048 sc0 sc1\n\t"
        "global_load_dwordx4 %9, %16, off offset:2304 sc0 sc1\n\t"
        "global_load_dwordx4 %10, %16, off offset:2560 sc0 sc1\n\t"
        "global_load_dwordx4 %11, %16, off offset:2816 sc0 sc1\n\t"
        "global_load_dwordx4 %12, %16, off offset:3072 sc0 sc1\n\t"
        "global_load_dwordx4 %13, %16, off offset:3328 sc0 sc1\n\t"
        "global_load_dwordx4 %14, %16, off offset:3584 sc0 sc1\n\t"
        "global_load_dwordx4 %15, %16, off offset:3840 sc0 sc1\n\t"
        "s_waitcnt vmcnt(0)"
        : "=&v"(a0), "=&v"(a1), "=&v"(a2), "=&v"(a3),
          "=&v"(a4), "=&v"(a5), "=&v"(a6), "=&v"(a7),
          "=&v"(a8), "=&v"(a9), "=&v"(a10), "=&v"(a11),
          "=&v"(a12), "=&v"(a13), "=&v"(a14), "=&v"(a15)
        : "v"(p)
        : "memory");
}

// ============================ embedding ============================
__global__ void embed_kernel(const int* __restrict__ ids,
                             const float* __restrict__ emb,
                             float* __restrict__ x0) {
    int bs = blockIdx.x;
    int id = ids[bs];
    const float* row = emb + (size_t)id * NEMB;
    float* out = x0 + (size_t)bs * NEMB;
    const float scale = 17.320508075688772f;   // sqrt(300)
    for (int e = threadIdx.x; e < NEMB; e += blockDim.x)
        out[e] = row[e] * scale;
}

// ============================ fp32 -> bf16 hi/lo split (RN), padded ============================
__global__ void conv_split(const float* __restrict__ src,
                           ushort_t* __restrict__ hi, ushort_t* __restrict__ lo,
                           int N, int K, int KP, int total) {
    for (int i = blockIdx.x * blockDim.x + threadIdx.x; i < total;
         i += gridDim.x * blockDim.x) {
        int r = i / KP, k = i - r * KP;
        float v = (r < N && k < K) ? src[(size_t)r * K + k] : 0.f;
        unsigned u = __float_as_uint(v);
        unsigned hb = (u + 0x7FFFu + ((u >> 16) & 1u)) >> 16;
        float hf = __uint_as_float(hb << 16);
        float rem = v - hf;
        unsigned u2 = __float_as_uint(rem);
        unsigned lb = (u2 + 0x7FFFu + ((u2 >> 16) & 1u)) >> 16;
        hi[i] = (ushort_t)hb;
        lo[i] = (ushort_t)lb;
    }
}

// ============================ bf16-split MFMA GEMM ============================
// C = A[M=4096,KP] * W[NP,KP]^T (+bias), via Ah*Wh + Ah*Wl + Al*Wh.
// 128x128 tile, 4 waves (2x2), each wave 64x64 = 4x4 16x16x32 fragments.
// permuted=1 -> C[(s*BB+b)*N + n] with m = b*256+s; col-guard n < N.
__global__ __launch_bounds__(256) void gemm_mfma(
        const ushort_t* __restrict__ Ah, const ushort_t* __restrict__ Al,
        const ushort_t* __restrict__ Wh, const ushort_t* __restrict__ Wl,
        float* __restrict__ C, int N, int KP,
        const float* __restrict__ bias_i, const float* __restrict__ bias_h,
        int permuted) {
    constexpr int LD = 40;             // LDS row stride (bf16): 32 + 8 pad
    __shared__ ushort_t sA[2][128 * LD];
    __shared__ ushort_t sW[2][128 * LD];
    const int t    = threadIdx.x;
    const int lane = t & 63;
    const int wave = t >> 6;
    const int wm   = wave >> 1, wn = wave & 1;
    const int n0   = blockIdx.x * 128;
    const int m0   = blockIdx.y * 128;

    f32x4 acc[4][4];
    #pragma unroll
    for (int i = 0; i < 4; i++)
        #pragma unroll
        for (int j = 0; j < 4; j++)
            acc[i][j] = (f32x4){0.f, 0.f, 0.f, 0.f};

    const int nkt = KP >> 5;
    for (int kt = 0; kt < nkt; kt++) {
        __syncthreads();
        #pragma unroll
        for (int c = 0; c < 2; c++) {
            int id = t + c * 256;          // 0..511
            int r = id >> 2, kq = id & 3;
            int so = r * LD + kq * 8;
            size_t goA = (size_t)(m0 + r) * KP + kt * 32 + kq * 8;
            size_t goW = (size_t)(n0 + r) * KP + kt * 32 + kq * 8;
            *reinterpret_cast<u4_t*>(&sA[0][so]) = *reinterpret_cast<const u4_t*>(Ah + goA);
            *reinterpret_cast<u4_t*>(&sA[1][so]) = *reinterpret_cast<const u4_t*>(Al + goA);
            *reinterpret_cast<u4_t*>(&sW[0][so]) = *reinterpret_cast<const u4_t*>(Wh + goW);
            *reinterpret_cast<u4_t*>(&sW[1][so]) = *reinterpret_cast<const u4_t*>(Wl + goW);
        }
        __syncthreads();

        bf16x8 ah[4], al[4], wh[4], wl[4];
        #pragma unroll
        for (int i = 0; i < 4; i++) {
            int ro = (wm * 64 + i * 16 + (lane & 15)) * LD + (lane >> 4) * 8;
            int co = (wn * 64 + i * 16 + (lane & 15)) * LD + (lane >> 4) * 8;
            ah[i] = *reinterpret_cast<const bf16x8*>(&sA[0][ro]);
            al[i] = *reinterpret_cast<const bf16x8*>(&sA[1][ro]);
            wh[i] = *reinterpret_cast<const bf16x8*>(&sW[0][co]);
            wl[i] = *reinterpret_cast<const bf16x8*>(&sW[1][co]);
        }
        #pragma unroll
        for (int i = 0; i < 4; i++)
            #pragma unroll
            for (int j = 0; j < 4; j++) {
                acc[i][j] = __builtin_amdgcn_mfma_f32_16x16x32_bf16(ah[i], wh[j], acc[i][j], 0, 0, 0);
                acc[i][j] = __builtin_amdgcn_mfma_f32_16x16x32_bf16(ah[i], wl[j], acc[i][j], 0, 0, 0);
                acc[i][j] = __builtin_amdgcn_mfma_f32_16x16x32_bf16(al[i], wh[j], acc[i][j], 0, 0, 0);
            }
    }

    // epilogue: C/D layout col=lane&15, row=(lane>>4)*4+reg
    #pragma unroll
    for (int i = 0; i < 4; i++) {
        int row = m0 + wm * 64 + i * 16 + ((lane >> 4) << 2);
        #pragma unroll
        for (int j = 0; j < 4; j++) {
            int col = n0 + wn * 64 + j * 16 + (lane & 15);
            if (col < N) {
                float bv = bias_i ? (bias_i[col] + bias_h[col]) : 0.f;
                #pragma unroll
                for (int r2 = 0; r2 < 4; r2++) {
                    int m = row + r2;
                    float v = acc[i][j][r2] + bv;
                    size_t idx;
                    if (permuted) {
                        int b_ = m >> 8;      // S = 256
                        int s_ = m & 255;
                        idx = ((size_t)s_ * BB + b_) * (size_t)N + col;
                    } else {
                        idx = (size_t)m * (size_t)N + col;
                    }
                    C[idx] = v;
                }
            }
        }
    }
}

// ============================ persistent LSTM recurrence (v6) ============================
// Thread (ks = t>>3, rg = t&7): partial dots for 3 gate rows over its k-slice.
// W streamed from L2 into transient regs. h exchanged as 16B {h0,h1,h2,tag}
// chunks, tiled [colgrp16][row16][col16] so one thread's 16 row-loads are a
// single asm bundle (base + imm offsets 0..3840) = 1 LLC RT; whole-bundle
// parallel retry. Gates+publish fused into the 32 publisher threads.
template<int SW, int NCHR>
__global__ __launch_bounds__(NT, 1) void lstm_rec(
        const float* __restrict__ Whh,   // [4H][H]
        const float* __restrict__ xg,    // [S][B][4H]
        float* __restrict__ xout,        // [B][S][H]
        u4_t* __restrict__ hx,           // [2][NSTR/16][16][16] chunks
        int H, unsigned TB) {
    constexpr int KP   = 48 * SW;        // padded K (>= H)
    constexpr int LDH  = KP + 4;         // ht row stride
    constexpr int NSUB = SW / 8;         // 8-col sub-phases per slice
    constexpr int PRS  = 17;             // pbuf row stride (conflict-free)
    constexpr int PSS  = 24 * PRS + 4;   // pbuf slot stride = 412
    extern __shared__ __align__(16) float lds[];
    float* ht   = lds;                   // [16][LDH]
    float* pbuf = ht + 16 * LDH;         // [24][PSS]
    float* gbuf = pbuf + 24 * PSS;       // [NT]   (row*16+b)
    float* cbuf = gbuf + NT;             // [96]   (l*16+b)

    const int t    = threadIdx.x;
    const int lane = t & 63;
    const int wv   = t >> 6;             // wave 0..5
    const int ks   = t >> 3;             // 0..47
    const int rg   = t & 7;              // 0..7
    const int h0   = blockIdx.x * CHUNK;
    const int G4   = 4 * H;

    // W row pointers (invalid rows clamped to row 0; results discarded later)
    const float* wr[3];
    #pragma unroll
    for (int j = 0; j < 3; j++) {
        int r = 3 * rg + j, g = r / CHUNK, l = r - g * CHUNK;
        int grow = ((h0 + l) < H) ? (g * H + h0 + l) : 0;
        wr[j] = Whh + (size_t)grow * (size_t)H;
    }

    // zero ht (covers pad cols / never-staged region) and c state
    for (int i = t; i < 16 * LDH; i += NT) ht[i] = 0.f;
    if (t < 96) cbuf[t] = 0.f;
    __syncthreads();

    // reducer role: (r_row = t>>4, r_b = t&15)
    const int r_row = t >> 4, r_b = t & 15;
    const int r_g = r_row / CHUNK, r_l = r_row - r_g * CHUNK;
    const int r_h = ((h0 + r_l) < H) ? (h0 + r_l) : h0;
    const float* xgp = xg + (size_t)r_b * G4 + (size_t)r_g * H + r_h;

    const int pairidx = (lane >> 4) & 3;
    const int prow3   = 3 * (lane & 7);

    // staging base chunk index for this thread's column t: (t>>4)*256 + (t&15)
    const int stg_base = (t >> 4) * 256 + (t & 15);

    #pragma unroll 1
    for (int s = 0; s < SS; s++) {
        const u4_t* hcb = hx + (size_t)(s & 1) * (16 * NSTR);        // consume
        u4_t*       hpb = hx + (size_t)((s + 1) & 1) * (16 * NSTR);  // produce
        const unsigned tgt = TB + (unsigned)s;
        float xgv = xgp[(size_t)s * (size_t)(16 * G4)];

        // ---- stage h tile: one 16-load bundle, parallel whole-bundle retry ----
        if (s > 0 && t < NCHR) {
            const u4_t* p = hcb + stg_base;
            u4_t u0, u1, u2, u3, u4v, u5v, u6v, u7v;
            u4_t u8v, u9v, u10v, u11v, u12v, u13v, u14v, u15v;
            for (;;) {
                llc_load16_wait(u0, u1, u2, u3, u4v, u5v, u6v, u7v,
                                u8v, u9v, u10v, u11v, u12v, u13v, u14v, u15v, p);
                int ok = (u0.w  >= tgt) & (u1.w  >= tgt) & (u2.w  >= tgt) & (u3.w  >= tgt)
                       & (u4v.w >= tgt) & (u5v.w >= tgt) & (u6v.w >= tgt) & (u7v.w >= tgt)
                       & (u8v.w >= tgt) & (u9v.w >= tgt) & (u10v.w >= tgt) & (u11v.w >= tgt)
                       & (u12v.w >= tgt) & (u13v.w >= tgt) & (u14v.w >= tgt) & (u15v.w >= tgt);
                if (ok) break;
            }
            float* d;
            d = ht +  0 * LDH + 3 * t; d[0] = __uint_as_float(u0.x);  d[1] = __uint_as_float(u0.y);  d[2] = __uint_as_float(u0.z);
            d = ht +  1 * LDH + 3 * t; d[0] = __uint_as_float(u1.x);  d[1] = __uint_as_float(u1.y);  d[2] = __uint_as_float(u1.z);
            d = ht +  2 * LDH + 3 * t; d[0] = __uint_as_float(u2.x);  d[1] = __uint_as_float(u2.y);  d[2] = __uint_as_float(u2.z);
            d = ht +  3 * LDH + 3 * t; d[0] = __uint_as_float(u3.x);  d[1] = __uint_as_float(u3.y);  d[2] = __uint_as_float(u3.z);
            d = ht +  4 * LDH + 3 * t; d[0] = __uint_as_float(u4v.x); d[1] = __uint_as_float(u4v.y); d[2] = __uint_as_float(u4v.z);
            d = ht +  5 * LDH + 3 * t; d[0] = __uint_as_float(u5v.x); d[1] = __uint_as_float(u5v.y); d[2] = __uint_as_float(u5v.z);
            d = ht +  6 * LDH + 3 * t; d[0] = __uint_as_float(u6v.x); d[1] = __uint_as_float(u6v.y); d[2] = __uint_as_float(u6v.z);
            d = ht +  7 * LDH + 3 * t; d[0] = __uint_as_float(u7v.x); d[1] = __uint_as_float(u7v.y); d[2] = __uint_as_float(u7v.z);
            d = ht +  8 * LDH + 3 * t; d[0] = __uint_as_float(u8v.x); d[1] = __uint_as_float(u8v.y); d[2] = __uint_as_float(u8v.z);
            d = ht +  9 * LDH + 3 * t; d[0] = __uint_as_float(u9v.x); d[1] = __uint_as_float(u9v.y); d[2] = __uint_as_float(u9v.z);
            d = ht + 10 * LDH + 3 * t; d[0] = __uint_as_float(u10v.x); d[1] = __uint_as_float(u10v.y); d[2] = __uint_as_float(u10v.z);
            d = ht + 11 * LDH + 3 * t; d[0] = __uint_as_float(u11v.x); d[1] = __uint_as_float(u11v.y); d[2] = __uint_as_float(u11v.z);
            d = ht + 12 * LDH + 3 * t; d[0] = __uint_as_float(u12v.x); d[1] = __uint_as_float(u12v.y); d[2] = __uint_as_float(u12v.z);
            d = ht + 13 * LDH + 3 * t; d[0] = __uint_as_float(u13v.x); d[1] = __uint_as_float(u13v.y); d[2] = __uint_as_float(u13v.z);
            d = ht + 14 * LDH + 3 * t; d[0] = __uint_as_float(u14v.x); d[1] = __uint_as_float(u14v.y); d[2] = __uint_as_float(u14v.z);
            d = ht + 15 * LDH + 3 * t; d[0] = __uint_as_float(u15v.x); d[1] = __uint_as_float(u15v.y); d[2] = __uint_as_float(u15v.z);
        }
        __syncthreads();

        // ---- per-thread partial dots (W streamed from L2, h from LDS) ----
        float a[3][16];
        #pragma unroll
        for (int j = 0; j < 3; j++)
            #pragma unroll
            for (int b = 0; b < 16; b++) a[j][b] = 0.f;

        if (s > 0) {
            #pragma unroll
            for (int sub = 0; sub < NSUB; sub++) {
                const int kk = ks * SW + sub * 8;
                const int k0 = (kk < H) ? kk : 0;          // clamp; h=0 in pad
                const int k1 = (kk + 4 < H) ? (kk + 4) : 0;
                const f4_t w00 = load_f4u(wr[0] + k0), w01 = load_f4u(wr[0] + k1);
                const f4_t w10 = load_f4u(wr[1] + k0), w11 = load_f4u(wr[1] + k1);
                const f4_t w20 = load_f4u(wr[2] + k0), w21 = load_f4u(wr[2] + k1);
                const float* hb = ht + kk;
                #pragma unroll
                for (int b = 0; b < 16; b++) {
                    const f4_t h0v = *reinterpret_cast<const f4_t*>(hb + b * LDH);
                    const f4_t h1v = *reinterpret_cast<const f4_t*>(hb + b * LDH + 4);
                    float acc;
                    acc = a[0][b];
                    acc = fmaf(w00.x, h0v.x, acc); acc = fmaf(w00.y, h0v.y, acc);
                    acc = fmaf(w00.z, h0v.z, acc); acc = fmaf(w00.w, h0v.w, acc);
                    acc = fmaf(w01.x, h1v.x, acc); acc = fmaf(w01.y, h1v.y, acc);
                    acc = fmaf(w01.z, h1v.z, acc); acc = fmaf(w01.w, h1v.w, acc);
                    a[0][b] = acc;
                    acc = a[1][b];
                    acc = fmaf(w10.x, h0v.x, acc); acc = fmaf(w10.y, h0v.y, acc);
                    acc = fmaf(w10.z, h0v.z, acc); acc = fmaf(w10.w, h0v.w, acc);
                    acc = fmaf(w11.x, h1v.x, acc); acc = fmaf(w11.y, h1v.y, acc);
                    acc = fmaf(w11.z, h1v.z, acc); acc = fmaf(w11.w, h1v.w, acc);
                    a[1][b] = acc;
                    acc = a[2][b];
                    acc = fmaf(w20.x, h0v.x, acc); acc = fmaf(w20.y, h0v.y, acc);
                    acc = fmaf(w20.z, h0v.z, acc); acc = fmaf(w20.w, h0v.w, acc);
                    acc = fmaf(w21.x, h1v.x, acc); acc = fmaf(w21.y, h1v.y, acc);
                    acc = fmaf(w21.z, h1v.z, acc); acc = fmaf(w21.w, h1v.w, acc);
                    a[2][b] = acc;
                }
            }
        }

        // ---- reduce k-slices: 1 shfl level (ks pairs) -> 24-slot pbuf ----
        #pragma unroll
        for (int j = 0; j < 3; j++)
            #pragma unroll
            for (int b = 0; b < 16; b++) {
                float v = a[j][b] + __shfl_xor(a[j][b], 8);
                if ((lane & 8) == 0)
                    pbuf[(wv * 4 + pairidx) * PSS + (prow3 + j) * PRS + b] = v;
            }
        __syncthreads();

        // ---- final reduce + bias from xg ----
        {
            float dot = xgv;
            #pragma unroll
            for (int q = 0; q < 24; q++)
                dot += pbuf[q * PSS + r_row * PRS + r_b];
            gbuf[t] = dot;
        }
        __syncthreads();

        // ---- fused gates + xout + publish (32 publisher threads) ----
        if (t < 32) {
            const int b = t & 15, cj = t >> 4;
            float hv3[3];
            #pragma unroll
            for (int i = 0; i < 3; i++) {
                int l = 3 * cj + i;
                float gi = gbuf[(0 * CHUNK + l) * 16 + b];
                float gf = gbuf[(1 * CHUNK + l) * 16 + b];
                float gg = gbuf[(2 * CHUNK + l) * 16 + b];
                float go = gbuf[(3 * CHUNK + l) * 16 + b];
                float iv = 1.f / (1.f + expf(-gi));
                float fv = 1.f / (1.f + expf(-gf));
                float gv = tanhf(gg);
                float ov = 1.f / (1.f + expf(-go));
                int ci = l * 16 + b;
                float c = fv * cbuf[ci] + iv * gv;
                cbuf[ci] = c;
                float hv = ov * tanhf(c);
                int hidx = h0 + l;
                if (hidx >= H) hv = 0.f;
                hv3[i] = hv;
                if (hidx < H)
                    xout[(size_t)b * ((size_t)SS * H) + (size_t)s * H + hidx] = hv;
            }
            u4_t pk;
            pk.x = __float_as_uint(hv3[0]);
            pk.y = __float_as_uint(hv3[1]);
            pk.z = __float_as_uint(hv3[2]);
            pk.w = tgt + 1u;
            int c = (h0 / 3) + cj;
            llc_store_u4_drain(hpb + ((c >> 4) * 256 + b * 16 + (c & 15)), pk);
        }
        // no extra sync: next step's staging sync orders ht/gbuf/pbuf reuse
    }
}

// ============================ launch ============================
extern "C" void kernel_launch(void* const* d_in, const int* in_sizes, int n_in,
                              void* d_out, int out_size, void* d_ws, size_t ws_size,
                              hipStream_t stream) {
    const int*   ids  = (const int*)d_in[0];
    const float* emb  = (const float*)d_in[1];
    const float* Wih0 = (const float*)d_in[2];
    const float* Whh0 = (const float*)d_in[3];
    const float* bih0 = (const float*)d_in[4];
    const float* bhh0 = (const float*)d_in[5];
    const float* Wih1 = (const float*)d_in[6];
    const float* Whh1 = (const float*)d_in[7];
    const float* bih1 = (const float*)d_in[8];
    const float* bhh1 = (const float*)d_in[9];
    const float* Wih2 = (const float*)d_in[10];
    const float* Whh2 = (const float*)d_in[11];
    const float* bih2 = (const float*)d_in[12];
    const float* bhh2 = (const float*)d_in[13];
    float* out = (float*)d_out;

    // workspace layout (floats)
    float* ws = (float*)d_ws;
    float* xA = ws;                        // 1,228,800  (x0, later x3)
    float* xB = xA + 1228800;              // 4,710,400  (x1, later x2; then final Ah/Al)
    float* xg = xB + 4710400;              // 18,841,600 (gates; then final Wh/Wl)
    u4_t*  hx = (u4_t*)(xg + 18841600);    // [2][6144] chunks = 196,608 B
    (void)in_sizes; (void)n_in; (void)out_size; (void)ws_size;

    // d_out as scratch for input-projection splits (fully rewritten at the end)
    ushort_t* sc  = (ushort_t*)d_out;
    ushort_t* tAh = sc;                               // [4096][1152] max
    ushort_t* tAl = tAh + (size_t)4096 * 1152;
    ushort_t* W0h = tAl + (size_t)4096 * 1152;        // [4608][320]
    ushort_t* W0l = W0h + (size_t)4608 * 320;
    ushort_t* W1h = W0l + (size_t)4608 * 320;         // [4608][1152]
    ushort_t* W1l = W1h + (size_t)4608 * 1152;
    ushort_t* W2h = W1l + (size_t)4608 * 1152;        // [1280][1152]
    ushort_t* W2l = W2h + (size_t)1280 * 1152;

    // final-projection splits (workspace regions dead by then)
    ushort_t* fAh = (ushort_t*)xB;                    // [4096][320]
    ushort_t* fAl = fAh + (size_t)4096 * 320;
    ushort_t* fWh = (ushort_t*)xg;                    // [32000][320]
    ushort_t* fWl = fWh + (size_t)32000 * 320;

    // zero tags once per launch (graph-captured, replay-safe)
    hipMemsetAsync(hx, 0, (size_t)2 * 16 * NSTR * 16, stream);

    // LDS bytes
    const size_t lds01 = (size_t)(16 * 1156 + 24 * 412 + NT + 96) * 4;  // 115,456
    const size_t lds2  = (size_t)(16 * 388  + 24 * 412 + NT + 96) * 4;  //  66,304

    // ---- static weight splits ----
    conv_split<<<dim3(720), dim3(256), 0, stream>>>(Wih0, W0h, W0l, 4600, 300, 320, 4608 * 320);
    conv_split<<<dim3(2048), dim3(256), 0, stream>>>(Wih1, W1h, W1l, 4600, 1150, 1152, 4608 * 1152);
    conv_split<<<dim3(720), dim3(256), 0, stream>>>(Wih2, W2h, W2l, 1200, 1150, 1152, 1280 * 1152);

    // ---- embedding ----
    embed_kernel<<<dim3(BB * SS), dim3(256), 0, stream>>>(ids, emb, xA);

    // ---- layer 0 ----
    conv_split<<<dim3(640), dim3(256), 0, stream>>>(xA, tAh, tAl, 4096, 300, 320, 4096 * 320);
    gemm_mfma<<<dim3(36, 32), dim3(256), 0, stream>>>(tAh, tAl, W0h, W0l, xg,
                                                      4600, 320, bih0, bhh0, 1);
    lstm_rec<24, 384><<<dim3(192), dim3(NT), lds01, stream>>>(Whh0, xg, xB, hx, 1150, 0u);

    // ---- layer 1 ----
    conv_split<<<dim3(2048), dim3(256), 0, stream>>>(xB, tAh, tAl, 4096, 1150, 1152, 4096 * 1152);
    gemm_mfma<<<dim3(36, 32), dim3(256), 0, stream>>>(tAh, tAl, W1h, W1l, xg,
                                                      4600, 1152, bih1, bhh1, 1);
    lstm_rec<24, 384><<<dim3(192), dim3(NT), lds01, stream>>>(Whh1, xg, xB, hx, 1150, 256u);

    // ---- layer 2 ----
    conv_split<<<dim3(2048), dim3(256), 0, stream>>>(xB, tAh, tAl, 4096, 1150, 1152, 4096 * 1152);
    gemm_mfma<<<dim3(10, 32), dim3(256), 0, stream>>>(tAh, tAl, W2h, W2l, xg,
                                                      1200, 1152, bih2, bhh2, 1);
    lstm_rec<8, 100><<<dim3(50), dim3(NT), lds2, stream>>>(Whh2, xg, xA, hx, 300, 512u);

    // ---- final projection splits (xB/xg dead; d_out scratch no longer needed) ----
    conv_split<<<dim3(640), dim3(256), 0, stream>>>(xA, fAh, fAl, 4096, 300, 320, 4096 * 320);
    conv_split<<<dim3(2048), dim3(256), 0, stream>>>(emb, fWh, fWl, 32000, 300, 320, 32000 * 320);

    // ---- tied output projection via bf16-split MFMA ----
    gemm_mfma<<<dim3(250, 32), dim3(256), 0, stream>>>(fAh, fAl, fWh, fWl, out,
                                                       NVOCAB, 320, nullptr, nullptr, 0);
}

// Round 10
// 8437.548 us; speedup vs baseline: 1.2930x; 1.2930x over previous
//
#include <hip/hip_runtime.h>

#define BB 16
#define SS 256
#define NVOCAB 32000
#define NEMB 300

// ---- recurrence geometry ----
#define CHUNK 6            // h-indices per block (multiple of 3: chunk-aligned publish)
#define NT 384             // threads per rec block (48 k-slices x 8 row-groups)
#define NSTR 384           // hx chunk stride per batch row

typedef float f4_t __attribute__((ext_vector_type(4)));
typedef unsigned int u4_t __attribute__((ext_vector_type(4)));
typedef short bf16x8 __attribute__((ext_vector_type(8)));
typedef float f32x4 __attribute__((ext_vector_type(4)));
typedef unsigned short ushort_t;

// unaligned-safe float4 global load (rows of W are only 4B-aligned when H=1150)
__device__ __forceinline__ f4_t load_f4u(const float* p) {
    f4_t v;
    __builtin_memcpy(&v, p, sizeof(f4_t));
    return v;
}

// LLC-coherent publish: 16B store (value+tag atomic at LLC) + drain inside asm
__device__ __forceinline__ void llc_store_u4_drain(u4_t* p, u4_t v) {
    asm volatile("global_store_dwordx4 %0, %1, off sc0 sc1\n\t"
                 "s_waitcnt vmcnt(0)" :: "v"(p), "v"(v) : "memory");
}

// Bundled coherent loads: 8 x dwordx4 issued and WAITED inside one asm block.
// No in-flight destination register ever crosses compiler-visible code.
__device__ __forceinline__ void llc_load8_wait(
        u4_t& u0, u4_t& u1, u4_t& u2, u4_t& u3,
        u4_t& u4v, u4_t& u5v, u4_t& u6v, u4_t& u7v,
        const u4_t* p0, const u4_t* p1, const u4_t* p2, const u4_t* p3,
        const u4_t* p4, const u4_t* p5, const u4_t* p6, const u4_t* p7) {
    asm volatile(
        "global_load_dwordx4 %0, %8, off sc0 sc1\n\t"
        "global_load_dwordx4 %1, %9, off sc0 sc1\n\t"
        "global_load_dwordx4 %2, %10, off sc0 sc1\n\t"
        "global_load_dwordx4 %3, %11, off sc0 sc1\n\t"
        "global_load_dwordx4 %4, %12, off sc0 sc1\n\t"
        "global_load_dwordx4 %5, %13, off sc0 sc1\n\t"
        "global_load_dwordx4 %6, %14, off sc0 sc1\n\t"
        "global_load_dwordx4 %7, %15, off sc0 sc1\n\t"
        "s_waitcnt vmcnt(0)"
        : "=&v"(u0), "=&v"(u1), "=&v"(u2), "=&v"(u3),
          "=&v"(u4v), "=&v"(u5v), "=&v"(u6v), "=&v"(u7v)
        : "v"(p0), "v"(p1), "v"(p2), "v"(p3),
          "v"(p4), "v"(p5), "v"(p6), "v"(p7)
        : "memory");
}

// ============================ embedding ============================
__global__ void embed_kernel(const int* __restrict__ ids,
                             const float* __restrict__ emb,
                             float* __restrict__ x0) {
    int bs = blockIdx.x;
    int id = ids[bs];
    const float* row = emb + (size_t)id * NEMB;
    float* out = x0 + (size_t)bs * NEMB;
    const float scale = 17.320508075688772f;   // sqrt(300)
    for (int e = threadIdx.x; e < NEMB; e += blockDim.x)
        out[e] = row[e] * scale;
}

// ============================ fp32 -> bf16 hi/lo split (RN), padded ============================
__global__ void conv_split(const float* __restrict__ src,
                           ushort_t* __restrict__ hi, ushort_t* __restrict__ lo,
                           int N, int K, int KP, int total) {
    for (int i = blockIdx.x * blockDim.x + threadIdx.x; i < total;
         i += gridDim.x * blockDim.x) {
        int r = i / KP, k = i - r * KP;
        float v = (r < N && k < K) ? src[(size_t)r * K + k] : 0.f;
        unsigned u = __float_as_uint(v);
        unsigned hb = (u + 0x7FFFu + ((u >> 16) & 1u)) >> 16;
        float hf = __uint_as_float(hb << 16);
        float rem = v - hf;
        unsigned u2 = __float_as_uint(rem);
        unsigned lb = (u2 + 0x7FFFu + ((u2 >> 16) & 1u)) >> 16;
        hi[i] = (ushort_t)hb;
        lo[i] = (ushort_t)lb;
    }
}

// ============================ bf16-split MFMA GEMM ============================
// C = A[M=4096,KP] * W[NP,KP]^T (+bias), via Ah*Wh + Ah*Wl + Al*Wh.
// 128x128 tile, 4 waves (2x2), each wave 64x64 = 4x4 16x16x32 fragments.
// permuted=1 -> C[(s*BB+b)*N + n] with m = b*256+s; col-guard n < N.
__global__ __launch_bounds__(256) void gemm_mfma(
        const ushort_t* __restrict__ Ah, const ushort_t* __restrict__ Al,
        const ushort_t* __restrict__ Wh, const ushort_t* __restrict__ Wl,
        float* __restrict__ C, int N, int KP,
        const float* __restrict__ bias_i, const float* __restrict__ bias_h,
        int permuted) {
    constexpr int LD = 40;             // LDS row stride (bf16): 32 + 8 pad
    __shared__ ushort_t sA[2][128 * LD];
    __shared__ ushort_t sW[2][128 * LD];
    const int t    = threadIdx.x;
    const int lane = t & 63;
    const int wave = t >> 6;
    const int wm   = wave >> 1, wn = wave & 1;
    const int n0   = blockIdx.x * 128;
    const int m0   = blockIdx.y * 128;

    f32x4 acc[4][4];
    #pragma unroll
    for (int i = 0; i < 4; i++)
        #pragma unroll
        for (int j = 0; j < 4; j++)
            acc[i][j] = (f32x4){0.f, 0.f, 0.f, 0.f};

    const int nkt = KP >> 5;
    for (int kt = 0; kt < nkt; kt++) {
        __syncthreads();
        #pragma unroll
        for (int c = 0; c < 2; c++) {
            int id = t + c * 256;          // 0..511
            int r = id >> 2, kq = id & 3;
            int so = r * LD + kq * 8;
            size_t goA = (size_t)(m0 + r) * KP + kt * 32 + kq * 8;
            size_t goW = (size_t)(n0 + r) * KP + kt * 32 + kq * 8;
            *reinterpret_cast<u4_t*>(&sA[0][so]) = *reinterpret_cast<const u4_t*>(Ah + goA);
            *reinterpret_cast<u4_t*>(&sA[1][so]) = *reinterpret_cast<const u4_t*>(Al + goA);
            *reinterpret_cast<u4_t*>(&sW[0][so]) = *reinterpret_cast<const u4_t*>(Wh + goW);
            *reinterpret_cast<u4_t*>(&sW[1][so]) = *reinterpret_cast<const u4_t*>(Wl + goW);
        }
        __syncthreads();

        bf16x8 ah[4], al[4], wh[4], wl[4];
        #pragma unroll
        for (int i = 0; i < 4; i++) {
            int ro = (wm * 64 + i * 16 + (lane & 15)) * LD + (lane >> 4) * 8;
            int co = (wn * 64 + i * 16 + (lane & 15)) * LD + (lane >> 4) * 8;
            ah[i] = *reinterpret_cast<const bf16x8*>(&sA[0][ro]);
            al[i] = *reinterpret_cast<const bf16x8*>(&sA[1][ro]);
            wh[i] = *reinterpret_cast<const bf16x8*>(&sW[0][co]);
            wl[i] = *reinterpret_cast<const bf16x8*>(&sW[1][co]);
        }
        #pragma unroll
        for (int i = 0; i < 4; i++)
            #pragma unroll
            for (int j = 0; j < 4; j++) {
                acc[i][j] = __builtin_amdgcn_mfma_f32_16x16x32_bf16(ah[i], wh[j], acc[i][j], 0, 0, 0);
                acc[i][j] = __builtin_amdgcn_mfma_f32_16x16x32_bf16(ah[i], wl[j], acc[i][j], 0, 0, 0);
                acc[i][j] = __builtin_amdgcn_mfma_f32_16x16x32_bf16(al[i], wh[j], acc[i][j], 0, 0, 0);
            }
    }

    // epilogue: C/D layout col=lane&15, row=(lane>>4)*4+reg
    #pragma unroll
    for (int i = 0; i < 4; i++) {
        int row = m0 + wm * 64 + i * 16 + ((lane >> 4) << 2);
        #pragma unroll
        for (int j = 0; j < 4; j++) {
            int col = n0 + wn * 64 + j * 16 + (lane & 15);
            if (col < N) {
                float bv = bias_i ? (bias_i[col] + bias_h[col]) : 0.f;
                #pragma unroll
                for (int r2 = 0; r2 < 4; r2++) {
                    int m = row + r2;
                    float v = acc[i][j][r2] + bv;
                    size_t idx;
                    if (permuted) {
                        int b_ = m >> 8;      // S = 256
                        int s_ = m & 255;
                        idx = ((size_t)s_ * BB + b_) * (size_t)N + col;
                    } else {
                        idx = (size_t)m * (size_t)N + col;
                    }
                    C[idx] = v;
                }
            }
        }
    }
}

// ============================ persistent LSTM recurrence (r7 structure, proven best) ============================
// Thread (ks = t>>3, rg = t&7): partial dots for 3 gate rows over its k-slice.
// W streamed from L2 into transient regs; h exchanged as 16B {h0,h1,h2,tag}
// chunks via sc0|sc1; two 8-load bundled issue+wait stages with whole-8
// parallel retry (measured best vs per-chunk spins and 16-bundles).
template<int SW, int NCHR>
__global__ __launch_bounds__(NT, 1) void lstm_rec(
        const float* __restrict__ Whh,   // [4H][H]
        const float* __restrict__ xg,    // [S][B][4H]
        float* __restrict__ xout,        // [B][S][H]
        u4_t* __restrict__ hx,           // [2][16][NSTR] chunks
        int H, unsigned TB) {
    constexpr int KP   = 48 * SW;        // padded K (>= H)
    constexpr int LDH  = KP + 4;         // ht row stride
    constexpr int NSUB = SW / 8;         // 8-col sub-phases per slice
    constexpr int PRS  = 17;             // pbuf row stride (conflict-free)
    constexpr int PSS  = 24 * PRS + 4;   // pbuf slot stride = 412
    extern __shared__ __align__(16) float lds[];
    float* ht   = lds;                   // [16][LDH]
    float* pbuf = ht + 16 * LDH;         // [24][PSS]
    float* gbuf = pbuf + 24 * PSS;       // [NT]   (row*16+b)
    float* cbuf = gbuf + NT;             // [96]
    float* hlx  = cbuf + 96;             // [96]

    const int t    = threadIdx.x;
    const int lane = t & 63;
    const int wv   = t >> 6;             // wave 0..5
    const int ks   = t >> 3;             // 0..47
    const int rg   = t & 7;              // 0..7
    const int h0   = blockIdx.x * CHUNK;
    const int G4   = 4 * H;

    // W row pointers (invalid rows clamped to row 0; results discarded later)
    const float* wr[3];
    #pragma unroll
    for (int j = 0; j < 3; j++) {
        int r = 3 * rg + j, g = r / CHUNK, l = r - g * CHUNK;
        int grow = ((h0 + l) < H) ? (g * H + h0 + l) : 0;
        wr[j] = Whh + (size_t)grow * (size_t)H;
    }

    // zero ht (covers pad cols / never-staged region) and c state
    for (int i = t; i < 16 * LDH; i += NT) ht[i] = 0.f;
    if (t < 96) cbuf[t] = 0.f;
    __syncthreads();

    // reducer/output role: (r_row = t>>4, r_b = t&15)
    const int r_row = t >> 4, r_b = t & 15;
    const int r_g = r_row / CHUNK, r_l = r_row - r_g * CHUNK;
    const int r_h = ((h0 + r_l) < H) ? (h0 + r_l) : h0;
    const float* xgp = xg + (size_t)r_b * G4 + (size_t)r_g * H + r_h;

    const int pairidx = (lane >> 4) & 3;
    const int prow3   = 3 * (lane & 7);

    #pragma unroll 1
    for (int s = 0; s < SS; s++) {
        const u4_t* hcb = hx + (size_t)(s & 1) * (16 * NSTR);        // consume
        u4_t*       hpb = hx + (size_t)((s + 1) & 1) * (16 * NSTR);  // produce
        const unsigned tgt = TB + (unsigned)s;
        float xgv = xgp[(size_t)s * (size_t)(16 * G4)];

        // ---- stage h tile (skip at s==0: ht stays zero) ----
        if (s > 0 && t < NCHR) {
            const u4_t* cb = hcb + t;
            #pragma unroll
            for (int rh = 0; rh < 2; rh++) {
                const u4_t* q0 = cb + (rh * 8 + 0) * NSTR;
                const u4_t* q1 = cb + (rh * 8 + 1) * NSTR;
                const u4_t* q2 = cb + (rh * 8 + 2) * NSTR;
                const u4_t* q3 = cb + (rh * 8 + 3) * NSTR;
                const u4_t* q4 = cb + (rh * 8 + 4) * NSTR;
                const u4_t* q5 = cb + (rh * 8 + 5) * NSTR;
                const u4_t* q6 = cb + (rh * 8 + 6) * NSTR;
                const u4_t* q7 = cb + (rh * 8 + 7) * NSTR;
                u4_t u0, u1, u2, u3, u4v, u5v, u6v, u7v;
                for (;;) {
                    llc_load8_wait(u0, u1, u2, u3, u4v, u5v, u6v, u7v,
                                   q0, q1, q2, q3, q4, q5, q6, q7);
                    int ok = (u0.w >= tgt) & (u1.w >= tgt) & (u2.w >= tgt) & (u3.w >= tgt)
                           & (u4v.w >= tgt) & (u5v.w >= tgt) & (u6v.w >= tgt) & (u7v.w >= tgt);
                    if (ok) break;
                }
                float* d;
                d = ht + (rh * 8 + 0) * LDH + 3 * t;
                d[0] = __uint_as_float(u0.x); d[1] = __uint_as_float(u0.y); d[2] = __uint_as_float(u0.z);
                d = ht + (rh * 8 + 1) * LDH + 3 * t;
                d[0] = __uint_as_float(u1.x); d[1] = __uint_as_float(u1.y); d[2] = __uint_as_float(u1.z);
                d = ht + (rh * 8 + 2) * LDH + 3 * t;
                d[0] = __uint_as_float(u2.x); d[1] = __uint_as_float(u2.y); d[2] = __uint_as_float(u2.z);
                d = ht + (rh * 8 + 3) * LDH + 3 * t;
                d[0] = __uint_as_float(u3.x); d[1] = __uint_as_float(u3.y); d[2] = __uint_as_float(u3.z);
                d = ht + (rh * 8 + 4) * LDH + 3 * t;
                d[0] = __uint_as_float(u4v.x); d[1] = __uint_as_float(u4v.y); d[2] = __uint_as_float(u4v.z);
                d = ht + (rh * 8 + 5) * LDH + 3 * t;
                d[0] = __uint_as_float(u5v.x); d[1] = __uint_as_float(u5v.y); d[2] = __uint_as_float(u5v.z);
                d = ht + (rh * 8 + 6) * LDH + 3 * t;
                d[0] = __uint_as_float(u6v.x); d[1] = __uint_as_float(u6v.y); d[2] = __uint_as_float(u6v.z);
                d = ht + (rh * 8 + 7) * LDH + 3 * t;
                d[0] = __uint_as_float(u7v.x); d[1] = __uint_as_float(u7v.y); d[2] = __uint_as_float(u7v.z);
            }
        }
        __syncthreads();

        // ---- per-thread partial dots (W streamed from L2, h from LDS) ----
        float a[3][16];
        #pragma unroll
        for (int j = 0; j < 3; j++)
            #pragma unroll
            for (int b = 0; b < 16; b++) a[j][b] = 0.f;

        if (s > 0) {
            #pragma unroll
            for (int sub = 0; sub < NSUB; sub++) {
                const int kk = ks * SW + sub * 8;
                const int k0 = (kk < H) ? kk : 0;          // clamp; h=0 in pad
                const int k1 = (kk + 4 < H) ? (kk + 4) : 0;
                const f4_t w00 = load_f4u(wr[0] + k0), w01 = load_f4u(wr[0] + k1);
                const f4_t w10 = load_f4u(wr[1] + k0), w11 = load_f4u(wr[1] + k1);
                const f4_t w20 = load_f4u(wr[2] + k0), w21 = load_f4u(wr[2] + k1);
                const float* hb = ht + kk;
                #pragma unroll
                for (int b = 0; b < 16; b++) {
                    const f4_t h0v = *reinterpret_cast<const f4_t*>(hb + b * LDH);
                    const f4_t h1v = *reinterpret_cast<const f4_t*>(hb + b * LDH + 4);
                    float acc;
                    acc = a[0][b];
                    acc = fmaf(w00.x, h0v.x, acc); acc = fmaf(w00.y, h0v.y, acc);
                    acc = fmaf(w00.z, h0v.z, acc); acc = fmaf(w00.w, h0v.w, acc);
                    acc = fmaf(w01.x, h1v.x, acc); acc = fmaf(w01.y, h1v.y, acc);
                    acc = fmaf(w01.z, h1v.z, acc); acc = fmaf(w01.w, h1v.w, acc);
                    a[0][b] = acc;
                    acc = a[1][b];
                    acc = fmaf(w10.x, h0v.x, acc); acc = fmaf(w10.y, h0v.y, acc);
                    acc = fmaf(w10.z, h0v.z, acc); acc = fmaf(w10.w, h0v.w, acc);
                    acc = fmaf(w11.x, h1v.x, acc); acc = fmaf(w11.y, h1v.y, acc);
                    acc = fmaf(w11.z, h1v.z, acc); acc = fmaf(w11.w, h1v.w, acc);
                    a[1][b] = acc;
                    acc = a[2][b];
                    acc = fmaf(w20.x, h0v.x, acc); acc = fmaf(w20.y, h0v.y, acc);
                    acc = fmaf(w20.z, h0v.z, acc); acc = fmaf(w20.w, h0v.w, acc);
                    acc = fmaf(w21.x, h1v.x, acc); acc = fmaf(w21.y, h1v.y, acc);
                    acc = fmaf(w21.z, h1v.z, acc); acc = fmaf(w21.w, h1v.w, acc);
                    a[2][b] = acc;
                }
            }
        }

        // ---- reduce k-slices: 1 shfl level (ks pairs) -> 24-slot pbuf ----
        #pragma unroll
        for (int j = 0; j < 3; j++)
            #pragma unroll
            for (int b = 0; b < 16; b++) {
                float v = a[j][b] + __shfl_xor(a[j][b], 8);
                if ((lane & 8) == 0)
                    pbuf[(wv * 4 + pairidx) * PSS + (prow3 + j) * PRS + b] = v;
            }
        __syncthreads();

        // ---- final reduce + bias from xg ----
        {
            float dot = xgv;
            #pragma unroll
            for (int q = 0; q < 24; q++)
                dot += pbuf[q * PSS + r_row * PRS + r_b];
            gbuf[t] = dot;
        }
        __syncthreads();

        // ---- gates ----
        if (t < 96) {
            int l = t >> 4, b = t & 15;
            float gi = gbuf[(0 * CHUNK + l) * 16 + b];
            float gf = gbuf[(1 * CHUNK + l) * 16 + b];
            float gg = gbuf[(2 * CHUNK + l) * 16 + b];
            float go = gbuf[(3 * CHUNK + l) * 16 + b];
            float iv = 1.f / (1.f + expf(-gi));
            float fv = 1.f / (1.f + expf(-gf));
            float gv = tanhf(gg);
            float ov = 1.f / (1.f + expf(-go));
            float c  = fv * cbuf[t] + iv * gv;
            cbuf[t]  = c;
            float hv = ov * tanhf(c);
            hv = ((h0 + l) < H) ? hv : 0.f;
            hlx[b * CHUNK + l] = hv;
            if ((h0 + l) < H)
                xout[(size_t)b * ((size_t)SS * H) + (size_t)s * H + (h0 + l)] = hv;
        }
        __syncthreads();

        // ---- pack + publish this block's 2 chunks per batch row ----
        if (t < 32) {
            int bq = t >> 1, cj = t & 1;
            u4_t pk;
            pk.x = __float_as_uint(hlx[bq * CHUNK + 3 * cj + 0]);
            pk.y = __float_as_uint(hlx[bq * CHUNK + 3 * cj + 1]);
            pk.z = __float_as_uint(hlx[bq * CHUNK + 3 * cj + 2]);
            pk.w = tgt + 1u;
            llc_store_u4_drain(hpb + bq * NSTR + (h0 / 3 + cj), pk);
        }
    }
}

// ============================ launch ============================
extern "C" void kernel_launch(void* const* d_in, const int* in_sizes, int n_in,
                              void* d_out, int out_size, void* d_ws, size_t ws_size,
                              hipStream_t stream) {
    const int*   ids  = (const int*)d_in[0];
    const float* emb  = (const float*)d_in[1];
    const float* Wih0 = (const float*)d_in[2];
    const float* Whh0 = (const float*)d_in[3];
    const float* bih0 = (const float*)d_in[4];
    const float* bhh0 = (const float*)d_in[5];
    const float* Wih1 = (const float*)d_in[6];
    const float* Whh1 = (const float*)d_in[7];
    const float* bih1 = (const float*)d_in[8];
    const float* bhh1 = (const float*)d_in[9];
    const float* Wih2 = (const float*)d_in[10];
    const float* Whh2 = (const float*)d_in[11];
    const float* bih2 = (const float*)d_in[12];
    const float* bhh2 = (const float*)d_in[13];
    float* out = (float*)d_out;

    // workspace layout (floats)
    float* ws = (float*)d_ws;
    float* xA = ws;                        // 1,228,800  (x0, later x3)
    float* xB = xA + 1228800;              // 4,710,400  (x1, later x2; then final Ah/Al)
    float* xg = xB + 4710400;              // 18,841,600 (gates; then final Wh/Wl)
    u4_t*  hx = (u4_t*)(xg + 18841600);    // [2][16][NSTR] chunks = 196,608 B
    (void)in_sizes; (void)n_in; (void)out_size; (void)ws_size;

    // d_out as scratch for input-projection splits (fully rewritten at the end)
    ushort_t* sc  = (ushort_t*)d_out;
    ushort_t* tAh = sc;                               // [4096][1152] max
    ushort_t* tAl = tAh + (size_t)4096 * 1152;
    ushort_t* W0h = tAl + (size_t)4096 * 1152;        // [4608][320]
    ushort_t* W0l = W0h + (size_t)4608 * 320;
    ushort_t* W1h = W0l + (size_t)4608 * 320;         // [4608][1152]
    ushort_t* W1l = W1h + (size_t)4608 * 1152;
    ushort_t* W2h = W1l + (size_t)4608 * 1152;        // [1280][1152]
    ushort_t* W2l = W2h + (size_t)1280 * 1152;

    // final-projection splits (workspace regions dead by then)
    ushort_t* fAh = (ushort_t*)xB;                    // [4096][320]
    ushort_t* fAl = fAh + (size_t)4096 * 320;
    ushort_t* fWh = (ushort_t*)xg;                    // [32000][320]
    ushort_t* fWl = fWh + (size_t)32000 * 320;

    // zero tags once per launch (graph-captured, replay-safe)
    hipMemsetAsync(hx, 0, (size_t)2 * 16 * NSTR * 16, stream);

    // LDS bytes
    const size_t lds01 = (size_t)(16 * 1156 + 24 * 412 + NT + 96 + 96) * 4;  // 115,840
    const size_t lds2  = (size_t)(16 * 388  + 24 * 412 + NT + 96 + 96) * 4;  //  66,688

    // ---- static weight splits ----
    conv_split<<<dim3(720), dim3(256), 0, stream>>>(Wih0, W0h, W0l, 4600, 300, 320, 4608 * 320);
    conv_split<<<dim3(2048), dim3(256), 0, stream>>>(Wih1, W1h, W1l, 4600, 1150, 1152, 4608 * 1152);
    conv_split<<<dim3(720), dim3(256), 0, stream>>>(Wih2, W2h, W2l, 1200, 1150, 1152, 1280 * 1152);

    // ---- embedding ----
    embed_kernel<<<dim3(BB * SS), dim3(256), 0, stream>>>(ids, emb, xA);

    // ---- layer 0 ----
    conv_split<<<dim3(640), dim3(256), 0, stream>>>(xA, tAh, tAl, 4096, 300, 320, 4096 * 320);
    gemm_mfma<<<dim3(36, 32), dim3(256), 0, stream>>>(tAh, tAl, W0h, W0l, xg,
                                                      4600, 320, bih0, bhh0, 1);
    lstm_rec<24, 384><<<dim3(192), dim3(NT), lds01, stream>>>(Whh0, xg, xB, hx, 1150, 0u);

    // ---- layer 1 ----
    conv_split<<<dim3(2048), dim3(256), 0, stream>>>(xB, tAh, tAl, 4096, 1150, 1152, 4096 * 1152);
    gemm_mfma<<<dim3(36, 32), dim3(256), 0, stream>>>(tAh, tAl, W1h, W1l, xg,
                                                      4600, 1152, bih1, bhh1, 1);
    lstm_rec<24, 384><<<dim3(192), dim3(NT), lds01, stream>>>(Whh1, xg, xB, hx, 1150, 256u);

    // ---- layer 2 ----
    conv_split<<<dim3(2048), dim3(256), 0, stream>>>(xB, tAh, tAl, 4096, 1150, 1152, 4096 * 1152);
    gemm_mfma<<<dim3(10, 32), dim3(256), 0, stream>>>(tAh, tAl, W2h, W2l, xg,
                                                      1200, 1152, bih2, bhh2, 1);
    lstm_rec<8, 100><<<dim3(50), dim3(NT), lds2, stream>>>(Whh2, xg, xA, hx, 300, 512u);

    // ---- final projection splits (xB/xg dead; d_out scratch no longer needed) ----
    conv_split<<<dim3(640), dim3(256), 0, stream>>>(xA, fAh, fAl, 4096, 300, 320, 4096 * 320);
    conv_split<<<dim3(2048), dim3(256), 0, stream>>>(emb, fWh, fWl, 32000, 300, 320, 32000 * 320);

    // ---- tied output projection via bf16-split MFMA ----
    gemm_mfma<<<dim3(250, 32), dim3(256), 0, stream>>>(fAh, fAl, fWh, fWl, out,
                                                       NVOCAB, 320, nullptr, nullptr, 0);
}